// Round 3
// baseline (43.975 us; speedup 1.0000x reference)
//
#include <hip/hip_runtime.h>
#include <stdint.h>

// Chamfer distance, B=4, N=M=8192, fp32 [B][N][3], out[B] = d01+d10.
//
// R3 (on the verified R2 MFMA formulation): d'(q,p) = q.p - 0.5|p|^2 as an
// exact-to-2^-18 bf16-split dot of length 14 <= K=16, one
// v_mfma_f32_32x32x16_bf16 per 32q x 32p tile.
// This round:
//  - max3 pair-merge: best = max3(best, d_t, d_t1) -> 8 VALU instr per mfma
//    (was 16; VALU demand now half the matrix-pipe demand).
//  - global_load_lds width-16 staging into a double-buffered LDS (32 KB),
//    ONE barrier per pass; next-pass loads fly under the compute phase.
//  - 5 dispatches -> 3: prep zeroes keys+out; final uses atomicAdd (2
//    deterministic addends per out[b]).

typedef __bf16 bf16x8 __attribute__((ext_vector_type(8)));
typedef float  f32x16 __attribute__((ext_vector_type(16)));

constexpr int B     = 4;
constexpr int NPTS  = 8192;
constexpr int BLOCK = 256;
constexpr int QPW   = 64;              // queries per wave (2 x 32-row A frags)
constexpr int QPB   = 256;             // 4 waves * 64
constexpr int QBLKS = NPTS / QPB;      // 32
constexpr int CH    = 4;               // point chunks per (b,dir)
constexpr int CPTS  = NPTS / CH;       // 2048 points per chunk
constexpr int SPTS  = 512;             // points per LDS pass (16 KB/buffer)
constexpr int NPASS = CPTS / SPTS;     // 4
constexpr int TPP   = SPTS / 32;       // 16 tiles per pass
constexpr int PASSBYTES = SPTS * 2 * 16;              // 16 KB
constexpr size_t KEYBYTES = (size_t)2 * B * NPTS * sizeof(unsigned);

__device__ inline unsigned key_of(float f) {
    unsigned b = __float_as_uint(f);
    return b ^ (unsigned)(((int)b >> 31) | (int)0x80000000u);
}
__device__ inline float float_of(unsigned k) {
    unsigned b = (k & 0x80000000u) ? (k ^ 0x80000000u) : ~k;
    return __uint_as_float(b);
}

__device__ inline void gload_lds16(const void* g, void* l) {
    __builtin_amdgcn_global_load_lds(
        (const __attribute__((address_space(1))) uint32_t*)g,
        (__attribute__((address_space(3))) uint32_t*)l, 16, 0, 0);
}

// ---- Kernel 1: prep point fragments; zero keys and out --------------------
// B-frag k-slots: g0(k0-7) = [pxh,pyh,pzh, pxl,pyl,pzl, pxh,pyh]
//                 g1(k8-15)= [pzh, nh, nl, pxl,pyl,pzl, 0, 0]
__global__ __launch_bounds__(BLOCK) void chamfer_prep(
    const float* __restrict__ tpl, const float* __restrict__ src,
    bf16x8* __restrict__ efrag,              // [8][NPTS][2]
    unsigned* __restrict__ keys, float* __restrict__ out)
{
    const int pt  = blockIdx.x * BLOCK + threadIdx.x;
    const int c   = blockIdx.y;              // dir*B + b
    const int b   = c & (B - 1);
    const int dir = c >> 2;
    const float* db = (dir == 0 ? src : tpl) + (size_t)b * NPTS * 3;

    keys[(size_t)c * NPTS + pt] = 0u;        // key 0 == float -max
    if (blockIdx.x == 0 && c == 0 && threadIdx.x < B) out[threadIdx.x] = 0.f;

    float x = db[3 * pt], y = db[3 * pt + 1], z = db[3 * pt + 2];
    float n = -0.5f * (x * x + y * y + z * z);
    __bf16 hx = (__bf16)x, hy = (__bf16)y, hz = (__bf16)z;
    __bf16 lx = (__bf16)(x - (float)hx);
    __bf16 ly = (__bf16)(y - (float)hy);
    __bf16 lz = (__bf16)(z - (float)hz);
    __bf16 nh = (__bf16)n;
    __bf16 nl = (__bf16)(n - (float)nh);
    const __bf16 zb = (__bf16)0.0f;

    size_t base = ((size_t)c * NPTS + pt) * 2;
    efrag[base]     = (bf16x8){hx, hy, hz, lx, ly, lz, hx, hy};
    efrag[base + 1] = (bf16x8){hz, nh, nl, lx, ly, lz, zb, zb};
}

// ---- Kernel 2: MFMA sweep -------------------------------------------------
__global__ __launch_bounds__(BLOCK, 4) void chamfer_sweep(
    const float* __restrict__ tpl, const float* __restrict__ src,
    const bf16x8* __restrict__ efrag,
    unsigned* __restrict__ keys)             // [2*B][NPTS], key of max d'
{
    __shared__ bf16x8 sbuf[2][SPTS * 2];     // 2 x 16 KB, linear (pt,g) order

    const int tid = threadIdx.x;
    const int l   = tid & 63;
    const int w   = tid >> 6;
    const int h   = l >> 5;                  // k-group (0: k0-7, 1: k8-15)
    const int r32 = l & 31;                  // A row / B col within tile
    const int c   = blockIdx.z;              // dir*B + b
    const int b   = c & (B - 1);
    const int dir = c >> 2;
    const float* q = (dir == 0 ? tpl : src) + (size_t)b * NPTS * 3;
    const int qbase = blockIdx.x * QPB + w * QPW;
    const char* eb  = (const char*)(efrag + ((size_t)c * NPTS + blockIdx.y * CPTS) * 2);

    // Prologue: issue pass-0 staging first so HBM/L2 latency hides under
    // the A-fragment build below. Wave w covers bytes [w*4KB, w*4KB+4KB).
    #pragma unroll
    for (int i = 0; i < 4; ++i) {
        int off = (w * 4 + i) * 1024;
        gload_lds16(eb + off + l * 16, (char*)&sbuf[0][0] + off);
    }

    // A fragments: row = l&31, k = h*8 + e. 64 queries per wave.
    // g0 = [qxh,qyh,qzh, qxh,qyh,qzh, qxl,qyl]; g1 = [qzl,1,1, qxl,qyl,qzl,0,0]
    const __bf16 one = (__bf16)1.0f, zb = (__bf16)0.0f;
    bf16x8 fa[2];
    #pragma unroll
    for (int f = 0; f < 2; ++f) {
        int qi = qbase + f * 32 + r32;
        float x = q[3 * qi], y = q[3 * qi + 1], z = q[3 * qi + 2];
        __bf16 hx = (__bf16)x, hy = (__bf16)y, hz = (__bf16)z;
        __bf16 lx = (__bf16)(x - (float)hx);
        __bf16 ly = (__bf16)(y - (float)hy);
        __bf16 lz = (__bf16)(z - (float)hz);
        if (h == 0) fa[f] = (bf16x8){hx, hy, hz, hx, hy, hz, lx, ly};
        else        fa[f] = (bf16x8){lz, one, one, lx, ly, lz, zb, zb};
    }

    f32x16 best0, best1, zc;
    #pragma unroll
    for (int r = 0; r < 16; ++r) { best0[r] = -3.4e38f; best1[r] = -3.4e38f; zc[r] = 0.0f; }

    const int idx = r32 * 2 + h;             // B-frag index within a tile
    for (int p = 0; p < NPASS; ++p) {
        // Drains vmcnt: pass-p loads (issued one full compute phase ago) are
        // in LDS; all waves are done reading the buffer we overwrite next.
        __syncthreads();
        if (p + 1 < NPASS) {
            const char* ebn = eb + (p + 1) * PASSBYTES;
            char* dst = (char*)&sbuf[(p + 1) & 1][0];
            #pragma unroll
            for (int i = 0; i < 4; ++i) {
                int off = (w * 4 + i) * 1024;
                gload_lds16(ebn + off + l * 16, dst + off);
            }
        }
        const bf16x8* sb = sbuf[p & 1];
        #pragma unroll
        for (int t = 0; t < TPP; t += 2) {
            bf16x8 bv0 = sb[t * 64 + idx];
            bf16x8 bv1 = sb[(t + 1) * 64 + idx];
            f32x16 d00 = __builtin_amdgcn_mfma_f32_32x32x16_bf16(fa[0], bv0, zc, 0, 0, 0);
            f32x16 d01 = __builtin_amdgcn_mfma_f32_32x32x16_bf16(fa[0], bv1, zc, 0, 0, 0);
            #pragma unroll
            for (int r = 0; r < 16; ++r)
                best0[r] = fmaxf(fmaxf(best0[r], d00[r]), d01[r]);   // v_max3
            f32x16 d10 = __builtin_amdgcn_mfma_f32_32x32x16_bf16(fa[1], bv0, zc, 0, 0, 0);
            f32x16 d11 = __builtin_amdgcn_mfma_f32_32x32x16_bf16(fa[1], bv1, zc, 0, 0, 0);
            #pragma unroll
            for (int r = 0; r < 16; ++r)
                best1[r] = fmaxf(fmaxf(best1[r], d10[r]), d11[r]);
        }
    }

    // Reduce over the 32 column-classes (lanes sharing h).
    #pragma unroll
    for (int m = 1; m < 32; m <<= 1) {
        #pragma unroll
        for (int r = 0; r < 16; ++r) {
            best0[r] = fmaxf(best0[r], __shfl_xor(best0[r], m, 64));
            best1[r] = fmaxf(best1[r], __shfl_xor(best1[r], m, 64));
        }
    }
    // D layout: col = lane&31, row = (r&3) + 8*(r>>2) + 4*h.
    if (r32 == 0) {
        unsigned* kz = keys + (size_t)c * NPTS;
        #pragma unroll
        for (int r = 0; r < 16; ++r) {
            int row = (r & 3) + 8 * (r >> 2) + 4 * h;
            atomicMax(&kz[qbase + row],      key_of(best0[r]));
            atomicMax(&kz[qbase + 32 + row], key_of(best1[r]));
        }
    }
}

// ---- Kernel 3: dist = |q|^2 - 2*maxd', mean, out[b] += (2 addends) --------
__global__ __launch_bounds__(256) void chamfer_final(
    const float* __restrict__ tpl, const float* __restrict__ src,
    const unsigned* __restrict__ keys, float* __restrict__ out)
{
    __shared__ float red[256];
    const int z = blockIdx.x;                // dir*B + b
    const float* qc = (z < B ? tpl : src) + (size_t)(z & (B - 1)) * NPTS * 3;

    float s = 0.f;
    for (int i = threadIdx.x; i < NPTS; i += 256) {
        float md = float_of(keys[(size_t)z * NPTS + i]);
        float x = qc[3 * i], y = qc[3 * i + 1], zz = qc[3 * i + 2];
        s += fmaf(md, -2.0f, x * x + y * y + zz * zz);
    }
    red[threadIdx.x] = s;
    __syncthreads();
    #pragma unroll
    for (int off = 128; off > 0; off >>= 1) {
        if (threadIdx.x < off) red[threadIdx.x] += red[threadIdx.x + off];
        __syncthreads();
    }
    if (threadIdx.x == 0)
        atomicAdd(&out[z & (B - 1)], red[0] * (1.0f / NPTS));
}

extern "C" void kernel_launch(void* const* d_in, const int* in_sizes, int n_in,
                              void* d_out, int out_size, void* d_ws, size_t ws_size,
                              hipStream_t stream) {
    const float* tpl = (const float*)d_in[0];
    const float* src = (const float*)d_in[1];
    float* out = (float*)d_out;
    unsigned* keys = (unsigned*)d_ws;                          // 256 KB
    bf16x8* efrag  = (bf16x8*)((char*)d_ws + KEYBYTES);        // 2 MB

    chamfer_prep <<<dim3(NPTS / BLOCK, 2 * B), BLOCK, 0, stream>>>(tpl, src, efrag, keys, out);
    chamfer_sweep<<<dim3(QBLKS, CH, 2 * B),    BLOCK, 0, stream>>>(tpl, src, efrag, keys);
    chamfer_final<<<2 * B, 256, 0, stream>>>(tpl, src, keys, out);
}

// Round 4
// 39.778 us; speedup vs baseline: 1.1055x; 1.1055x over previous
//
#include <hip/hip_runtime.h>
#include <stdint.h>

// Chamfer distance, B=4, N=M=8192, fp32 [B][N][3], out[B] = d01+d10.
//
// R4 (verified R2/R3 MFMA numerics: d' = q.p - 0.5|p|^2 as bf16-split K=14
// dot, one v_mfma_f32_32x32x16_bf16 per 32q x 32p tile; matrix floor 6.9us).
// Fixes three LDS-pipe/atomic costs identified by model audit:
//  - efrag stored g-major per 32-pt group -> main-loop ds_read_b128 is
//    contiguous per half-wave (conflict-free; was 4-way aliased).
//  - epilogue: LDS transpose reduce (padded stride-36 rows, one thread per
//    query) replaces 320 wave-shuffles/wave (ds_swizzle burned ~60% of the
//    matrix budget on the LDS pipe).
//  - atomics eliminated: per-(chunk, qtile) slot in chunkmax[], plain
//    stores; final kernel maxes the 4 chunk values per query.
//  - sched_barrier(0) per pair-merge caps live D-tiles -> fits 128 VGPR at
//    4 blocks/CU (LDS 36.9KB also caps at 4; 1024 blocks = one full round).

typedef __bf16 bf16x8 __attribute__((ext_vector_type(8)));
typedef float  f32x16 __attribute__((ext_vector_type(16)));
typedef float  f32x4  __attribute__((ext_vector_type(4)));

constexpr int B     = 4;
constexpr int NPTS  = 8192;
constexpr int BLOCK = 256;
constexpr int QPW   = 64;              // queries per wave (2 x 32-row A frags)
constexpr int QPB   = 256;             // 4 waves * 64
constexpr int QBLKS = NPTS / QPB;      // 32
constexpr int CH    = 4;               // point chunks per (b,dir)
constexpr int CPTS  = NPTS / CH;       // 2048 points per chunk
constexpr int SPTS  = 512;             // points per LDS pass (16 KB/buffer)
constexpr int NPASS = CPTS / SPTS;     // 4
constexpr int TPP   = SPTS / 32;       // 16 tiles per pass
constexpr int GRPS  = NPTS / 32;       // 256 point-groups per cloud
constexpr int RSTRIDE = 36;            // padded f32 per reduce row (128B+16B)
constexpr int SMEMB = BLOCK * RSTRIDE * 4;            // 36864 B (> 2x16KB)
constexpr size_t CMBYTES = (size_t)2 * B * CH * NPTS * sizeof(float); // 1 MB

__device__ inline void gload_lds16(const void* g, void* l) {
    __builtin_amdgcn_global_load_lds(
        (const __attribute__((address_space(1))) uint32_t*)g,
        (__attribute__((address_space(3))) uint32_t*)l, 16, 0, 0);
}

// ---- Kernel 1: prep point fragments (g-major per 32-pt group); zero out ---
// group base (1024 B): frags g0 of pts 0..31, then frags g1 of pts 0..31.
// g0(k0-7) = [pxh,pyh,pzh, pxl,pyl,pzl, pxh,pyh]
// g1(k8-15)= [pzh, nh, nl, pxl,pyl,pzl, 0, 0]
__global__ __launch_bounds__(BLOCK) void chamfer_prep(
    const float* __restrict__ tpl, const float* __restrict__ src,
    bf16x8* __restrict__ efrag, float* __restrict__ out)
{
    const int pt  = blockIdx.x * BLOCK + threadIdx.x;
    const int c   = blockIdx.y;              // dir*B + b
    const int b   = c & (B - 1);
    const int dir = c >> 2;
    const float* db = (dir == 0 ? src : tpl) + (size_t)b * NPTS * 3;

    if (blockIdx.x == 0 && c == 0 && threadIdx.x < B) out[threadIdx.x] = 0.f;

    float x = db[3 * pt], y = db[3 * pt + 1], z = db[3 * pt + 2];
    float n = -0.5f * (x * x + y * y + z * z);
    __bf16 hx = (__bf16)x, hy = (__bf16)y, hz = (__bf16)z;
    __bf16 lx = (__bf16)(x - (float)hx);
    __bf16 ly = (__bf16)(y - (float)hy);
    __bf16 lz = (__bf16)(z - (float)hz);
    __bf16 nh = (__bf16)n;
    __bf16 nl = (__bf16)(n - (float)nh);
    const __bf16 zb = (__bf16)0.0f;

    const int gi = pt >> 5, sl = pt & 31;
    size_t gb = ((size_t)c * GRPS + gi) * 64;
    efrag[gb + sl]      = (bf16x8){hx, hy, hz, lx, ly, lz, hx, hy};
    efrag[gb + 32 + sl] = (bf16x8){hz, nh, nl, lx, ly, lz, zb, zb};
}

// ---- Kernel 2: MFMA sweep -------------------------------------------------
__global__ __launch_bounds__(BLOCK, 4) void chamfer_sweep(
    const float* __restrict__ tpl, const float* __restrict__ src,
    const bf16x8* __restrict__ efrag,
    float* __restrict__ cm)                  // [2*B][CH][NPTS] chunk maxima
{
    __shared__ char smem[SMEMB];             // sbuf (2x16KB) / reduce (36.9KB)

    const int tid = threadIdx.x;
    const int l   = tid & 63;
    const int w   = tid >> 6;
    const int h   = l >> 5;                  // k-group (0: k0-7, 1: k8-15)
    const int r32 = l & 31;                  // A row / B col within tile
    const int c   = blockIdx.z;              // dir*B + b
    const int b   = c & (B - 1);
    const int dir = c >> 2;
    const float* q = (dir == 0 ? tpl : src) + (size_t)b * NPTS * 3;
    const int qbase = blockIdx.x * QPB + w * QPW;
    const char* eb  = (const char*)efrag
                    + ((size_t)c * GRPS + blockIdx.y * (CPTS / 32)) * 1024;

    // Prologue: issue pass-0 staging first (latency hides under fa build).
    #pragma unroll
    for (int i = 0; i < 4; ++i) {
        int off = (w * 4 + i) * 1024;
        gload_lds16(eb + off + l * 16, smem + off);
    }

    // A fragments: row = r32, k = h*8 + e. 64 queries per wave.
    // g0 = [qxh,qyh,qzh, qxh,qyh,qzh, qxl,qyl]; g1 = [qzl,1,1, qxl,qyl,qzl,0,0]
    const __bf16 one = (__bf16)1.0f, zb = (__bf16)0.0f;
    bf16x8 fa[2];
    #pragma unroll
    for (int f = 0; f < 2; ++f) {
        int qi = qbase + f * 32 + r32;
        float x = q[3 * qi], y = q[3 * qi + 1], z = q[3 * qi + 2];
        __bf16 hx = (__bf16)x, hy = (__bf16)y, hz = (__bf16)z;
        __bf16 lx = (__bf16)(x - (float)hx);
        __bf16 ly = (__bf16)(y - (float)hy);
        __bf16 lz = (__bf16)(z - (float)hz);
        if (h == 0) fa[f] = (bf16x8){hx, hy, hz, hx, hy, hz, lx, ly};
        else        fa[f] = (bf16x8){lz, one, one, lx, ly, lz, zb, zb};
    }

    f32x16 best0, best1, zc;
    #pragma unroll
    for (int r = 0; r < 16; ++r) { best0[r] = -3.4e38f; best1[r] = -3.4e38f; zc[r] = 0.0f; }

    const int idx0 = h * 32 + r32;           // contiguous 16B/lane per half-wave
    for (int p = 0; p < NPASS; ++p) {
        __syncthreads();                     // pass-p loads landed; buffer free
        if (p + 1 < NPASS) {
            const char* ebn = eb + (size_t)(p + 1) * SPTS * 2 * 16;
            char* dst = smem + ((p + 1) & 1) * 16384;
            #pragma unroll
            for (int i = 0; i < 4; ++i) {
                int off = (w * 4 + i) * 1024;
                gload_lds16(ebn + off + l * 16, dst + off);
            }
        }
        const bf16x8* sb = (const bf16x8*)(smem + (p & 1) * 16384);
        #pragma unroll
        for (int t = 0; t < TPP; t += 2) {
            bf16x8 bv0 = sb[t * 64 + idx0];
            bf16x8 bv1 = sb[(t + 1) * 64 + idx0];
            f32x16 d0 = __builtin_amdgcn_mfma_f32_32x32x16_bf16(fa[0], bv0, zc, 0, 0, 0);
            f32x16 d1 = __builtin_amdgcn_mfma_f32_32x32x16_bf16(fa[0], bv1, zc, 0, 0, 0);
            #pragma unroll
            for (int r = 0; r < 16; ++r)
                best0[r] = fmaxf(fmaxf(best0[r], d0[r]), d1[r]);   // v_max3
            __builtin_amdgcn_sched_barrier(0);   // cap live D-tiles (VGPR fit)
            d0 = __builtin_amdgcn_mfma_f32_32x32x16_bf16(fa[1], bv0, zc, 0, 0, 0);
            d1 = __builtin_amdgcn_mfma_f32_32x32x16_bf16(fa[1], bv1, zc, 0, 0, 0);
            #pragma unroll
            for (int r = 0; r < 16; ++r)
                best1[r] = fmaxf(fmaxf(best1[r], d1[r]), d0[r]);
            __builtin_amdgcn_sched_barrier(0);
        }
    }

    // Epilogue: LDS transpose reduce (no wave shuffles, no atomics).
    // D layout: col = r32, row = (r&3) + 8*(r>>2) + 4*h.
    __syncthreads();                         // all waves done reading sbuf
    float* red = (float*)smem;
    #pragma unroll
    for (int r = 0; r < 16; ++r) {
        int row = (r & 3) + 8 * (r >> 2) + 4 * h;
        red[(w * 64 + row) * RSTRIDE + r32]      = best0[r];
        red[(w * 64 + 32 + row) * RSTRIDE + r32] = best1[r];
    }
    __syncthreads();
    const float* rr = red + tid * RSTRIDE;   // 144B stride: 2-way only (free)
    float m = -3.4e38f;
    #pragma unroll
    for (int j = 0; j < 8; ++j) {
        f32x4 v = *(const f32x4*)(rr + 4 * j);
        m = fmaxf(m, fmaxf(fmaxf(v.x, v.y), fmaxf(v.z, v.w)));
    }
    cm[((size_t)c * CH + blockIdx.y) * NPTS + blockIdx.x * QPB + tid] = m;
}

// ---- Kernel 3: dist = |q|^2 - 2*max_chunks(maxd'), mean, out[b] += --------
__global__ __launch_bounds__(256) void chamfer_final(
    const float* __restrict__ tpl, const float* __restrict__ src,
    const float* __restrict__ cm, float* __restrict__ out)
{
    __shared__ float red[256];
    const int z = blockIdx.x;                // dir*B + b
    const float* qc = (z < B ? tpl : src) + (size_t)(z & (B - 1)) * NPTS * 3;
    const float* cz = cm + (size_t)z * CH * NPTS;

    float s = 0.f;
    for (int i = threadIdx.x; i < NPTS; i += 256) {
        float md = fmaxf(fmaxf(cz[i], cz[NPTS + i]),
                         fmaxf(cz[2 * NPTS + i], cz[3 * NPTS + i]));
        float x = qc[3 * i], y = qc[3 * i + 1], zz = qc[3 * i + 2];
        s += fmaf(md, -2.0f, x * x + y * y + zz * zz);
    }
    red[threadIdx.x] = s;
    __syncthreads();
    #pragma unroll
    for (int off = 128; off > 0; off >>= 1) {
        if (threadIdx.x < off) red[threadIdx.x] += red[threadIdx.x + off];
        __syncthreads();
    }
    if (threadIdx.x == 0)
        atomicAdd(&out[z & (B - 1)], red[0] * (1.0f / NPTS));  // 2 addends/b
}

extern "C" void kernel_launch(void* const* d_in, const int* in_sizes, int n_in,
                              void* d_out, int out_size, void* d_ws, size_t ws_size,
                              hipStream_t stream) {
    const float* tpl = (const float*)d_in[0];
    const float* src = (const float*)d_in[1];
    float* out = (float*)d_out;
    float* cm      = (float*)d_ws;                             // 1 MB
    bf16x8* efrag  = (bf16x8*)((char*)d_ws + CMBYTES);         // 2 MB

    chamfer_prep <<<dim3(NPTS / BLOCK, 2 * B), BLOCK, 0, stream>>>(tpl, src, efrag, out);
    chamfer_sweep<<<dim3(QBLKS, CH, 2 * B),    BLOCK, 0, stream>>>(tpl, src, efrag, cm);
    chamfer_final<<<2 * B, 256, 0, stream>>>(tpl, src, cm, out);
}